// Round 3
// baseline (93.731 us; speedup 1.0000x reference)
//
#include <hip/hip_runtime.h>
#include <hip/hip_bf16.h>

typedef __attribute__((ext_vector_type(8))) short bf16x8;    // 8 bf16 = 4 VGPRs
typedef __attribute__((ext_vector_type(4))) float f32x4;
typedef __attribute__((ext_vector_type(16))) float f32x16;

#define BN 8192          // batch
#define DF 128           // feature dim
#define DG 64            // gathered dim
static constexpr float L2E = 1.44269504088896340736f;  // log2(e)
static constexpr float LN2 = 0.69314718055994530942f;

// R10: fragment-linear layout for 32x32x16 MFMA tiles.
// Per 32-row tile (2048 shorts = 4KB): element (row, k) lives at
//   tile*2048 + (k>>4)*512 + ((((k>>3)&1)*32 + (row&31))*8) + (k&7)
// i.e. lane = (k_hi8)*32 + m, elem c = k&7 -- the canonical A/B layout for
// v_mfma_f32_32x32x16_bf16 (lane = m + 32*(k>>3)); a wave's fragment load for
// K-step kk is base + kk*512 shorts + lane*16B -> contiguous 1KB.
__device__ __forceinline__ size_t frag_off32(int row, int d) {
  int tile = row >> 5;
  int kk = d >> 4, khi = (d >> 3) & 1, c = d & 7;
  return (size_t)tile * 2048 + (size_t)kk * 512 +
         (size_t)(khi * 32 + (row & 31)) * 8 + c;
}

// ---------------------------------------------------------------------------
// Kernel 1: gather columns, convert to bf16 (X-side pre-scaled by log2 e),
// write 32-row fragment-linear layout, exact fp32 diagonals, zero rowsum/out.
// One wave per row; coalesced float2 row loads + in-register __shfl gather.
// ---------------------------------------------------------------------------
__global__ __launch_bounds__(256) void gather_k(
    const float* __restrict__ a, const float* __restrict__ v,
    const int* __restrict__ aidx, const int* __restrict__ iidx,
    __hip_bfloat16* __restrict__ Xv, __hip_bfloat16* __restrict__ Ya,
    __hip_bfloat16* __restrict__ Xa, __hip_bfloat16* __restrict__ Yv,
    float* __restrict__ diag, float* __restrict__ rowsum,
    float* __restrict__ out) {
  int tid = threadIdx.x;
  int gid = blockIdx.x * 256 + tid;
  if (gid < 2 * BN) rowsum[gid] = 0.f;    // zero accumulators (ws is poisoned)
  if (gid == 0) out[0] = 0.f;             // d_out is poisoned too

  int lane = tid & 63;
  int row  = blockIdx.x * 4 + (tid >> 6); // 2048 blocks x 4 waves = 8192 rows
  int ka = aidx[lane];
  int ki = iidx[lane];

  // coalesced: lane l holds elements (2l, 2l+1) of this row of a and v
  float2 a2 = ((const float2*)(a + (size_t)row * DF))[lane];
  float2 v2 = ((const float2*)(v + (size_t)row * DF))[lane];

  // in-register gather: element k lives in lane k>>1, component k&1
  float axa = __shfl(a2.x, ka >> 1), aya = __shfl(a2.y, ka >> 1);
  float vxa = __shfl(v2.x, ka >> 1), vya = __shfl(v2.y, ka >> 1);
  float axi = __shfl(a2.x, ki >> 1), ayi = __shfl(a2.y, ki >> 1);
  float vxi = __shfl(v2.x, ki >> 1), vyi = __shfl(v2.y, ki >> 1);
  float aa = (ka & 1) ? aya : axa;   // audio_only        (S_v cols)
  float va = (ka & 1) ? vya : vxa;   // image_audio_only  (S_v rows)
  float ai = (ki & 1) ? ayi : axi;   // audio_image_only  (S_a rows)
  float vi = (ki & 1) ? vyi : vxi;   // image_only        (S_a cols)

  size_t fo = frag_off32(row, lane);
  Xv[fo] = __float2bfloat16(va * L2E);
  Ya[fo] = __float2bfloat16(aa);
  Xa[fo] = __float2bfloat16(ai * L2E);
  Yv[fo] = __float2bfloat16(vi);

  // exact fp32 diagonals: diag_v[i] = dot(v_gath_a[i], a_gath_a[i]), etc.
  float dv = va * aa;
  float da = ai * vi;
#pragma unroll
  for (int off = 32; off >= 1; off >>= 1) {
    dv += __shfl_xor(dv, off);
    da += __shfl_xor(da, off);
  }
  if (lane == 0) {
    diag[row]      = dv;
    diag[BN + row] = da;
  }
}

// ---------------------------------------------------------------------------
// Kernel 2: partial sum_j 2^(S_ij) via mfma_f32_32x32x16_bf16.
// R10: 16x16x32 -> 32x32x16. Rationale (R8/R9 post-mortem): kernel is
// issue/pipe-serial, not hazard-bound (compiler already pipelined exp2;
// occupancy 4->8 was null). 32x32x16 halves MFMA instruction count (32.3 vs
// 2x19.4 SIMD-cyc per 32 output cols), halves loop iterations (addressing
// VALU), and the explicit c0/c1 two-stage unroll eliminates register moves
// while overlapping tile jt's 4-deep MFMA chain with tile jt-1's 16 exp2.
// VGPR ~100 -> 4 waves/SIMD; grid (64,8,2) = 1024 blocks = 4/CU, no tail.
// C layout (verified m74/m101): col=lane&31, row=(reg&3)+8*(reg>>2)+4*(lane>>5).
// ---------------------------------------------------------------------------
__global__ __launch_bounds__(256, 4) void lse_main(
    const unsigned short* __restrict__ Xv, const unsigned short* __restrict__ Ya,
    const unsigned short* __restrict__ Xa, const unsigned short* __restrict__ Yv,
    float* __restrict__ rowsum) {
  const unsigned short* X;
  const unsigned short* Y;
  float* rs;
  if (blockIdx.z == 0) { X = Xv; Y = Ya; rs = rowsum; }
  else                 { X = Xa; Y = Yv; rs = rowsum + BN; }

  int tid  = threadIdx.x;
  int lane = tid & 63;
  int row0 = blockIdx.x * 128 + (tid >> 6) * 32;   // one 32-row tile per wave

  // A fragments: 4 K-steps of 16, 1KB contiguous per step
  const unsigned short* ap =
      X + (size_t)(row0 >> 5) * 2048 + (size_t)lane * 8;
  bf16x8 a[4];
#pragma unroll
  for (int kk = 0; kk < 4; ++kk) a[kk] = *(const bf16x8*)(ap + kk * 512);

  // B base: this block sweeps 32 j-tiles of 32 cols (1024 cols)
  const unsigned short* bbase =
      Y + (size_t)(blockIdx.y * 32) * 2048 + (size_t)lane * 8;

  const f32x16 zero16 = {};
  f32x16 part = {};
  bf16x8 b[4];

#define LOADB(T)                                                              \
  {                                                                           \
    const unsigned short* p = bbase + (size_t)(T) * 2048;                     \
    b[0] = *(const bf16x8*)p;                                                 \
    b[1] = *(const bf16x8*)(p + 512);                                         \
    b[2] = *(const bf16x8*)(p + 1024);                                        \
    b[3] = *(const bf16x8*)(p + 1536);                                        \
  }
#define CHAIN(DST)                                                            \
  {                                                                           \
    __builtin_amdgcn_s_setprio(1);                                            \
    DST = __builtin_amdgcn_mfma_f32_32x32x16_bf16(a[0], b[0], zero16, 0, 0, 0); \
    DST = __builtin_amdgcn_mfma_f32_32x32x16_bf16(a[1], b[1], DST, 0, 0, 0);  \
    DST = __builtin_amdgcn_mfma_f32_32x32x16_bf16(a[2], b[2], DST, 0, 0, 0);  \
    DST = __builtin_amdgcn_mfma_f32_32x32x16_bf16(a[3], b[3], DST, 0, 0, 0);  \
    __builtin_amdgcn_s_setprio(0);                                            \
  }
#define EXPACC(C)                                                             \
  {                                                                           \
    _Pragma("unroll") for (int r = 0; r < 16; ++r)                            \
        part[r] += __builtin_amdgcn_exp2f(C[r]);                              \
  }

  f32x16 c0, c1;
  // prologue: tile 0 -> c0, prefetch tile 1
  LOADB(0)
  CHAIN(c0)
  LOADB(1)
  // steady state: 15 iterations x 2 tiles; loads stay exactly 1 tile ahead
  for (int i = 0; i < 15; ++i) {
    int t = 2 * i + 1;
    CHAIN(c1)            // tile t
    LOADB(t + 1)
    EXPACC(c0)           // tile t-1
    CHAIN(c0)            // tile t+1
    LOADB(t + 2)         // max t=29 -> loads tile 31; no overrun
    EXPACC(c1)           // tile t
  }
  // epilogue: tile 31 in b
  CHAIN(c1)
  EXPACC(c0)             // tile 30
  EXPACC(c1)             // tile 31
#undef LOADB
#undef CHAIN
#undef EXPACC

  // row sums: reduce part[r] across the 32 lanes of each half (cols)
#pragma unroll
  for (int off = 1; off < 32; off <<= 1) {
#pragma unroll
    for (int r = 0; r < 16; ++r)
      part[r] += __shfl_xor(part[r], off);
  }
  if ((lane & 31) == 0) {
    int hi = lane >> 5;
#pragma unroll
    for (int r = 0; r < 16; ++r) {
      int row = (r & 3) + 8 * (r >> 2) + 4 * hi;
      atomicAdd(&rs[row0 + row], part[r]);
    }
  }
}

// ---------------------------------------------------------------------------
// Kernel 3: 64-block finalize: out += sum(ln2*log2(rowsum) - diag) / BN
// (d_out zeroed by gather_k). __builtin_amdgcn_logf IS v_log_f32 = log2.
// ---------------------------------------------------------------------------
__global__ __launch_bounds__(256) void finalize_k(
    const float* __restrict__ rowsum, const float* __restrict__ diag,
    float* __restrict__ out) {
  int i = blockIdx.x * 256 + threadIdx.x;          // 64*256 = 16384 = 2*BN
  float local = LN2 * __builtin_amdgcn_logf(rowsum[i]) - diag[i];
#pragma unroll
  for (int off = 32; off >= 1; off >>= 1) local += __shfl_xor(local, off);
  __shared__ float red[4];
  int wave = threadIdx.x >> 6;
  if ((threadIdx.x & 63) == 0) red[wave] = local;
  __syncthreads();
  if (threadIdx.x == 0) {
    float bs = red[0] + red[1] + red[2] + red[3];
    atomicAdd(out, bs * (1.f / (float)BN));
  }
}

// ---------------------------------------------------------------------------
extern "C" void kernel_launch(void* const* d_in, const int* in_sizes, int n_in,
                              void* d_out, int out_size, void* d_ws, size_t ws_size,
                              hipStream_t stream) {
  const float* a   = (const float*)d_in[0];
  const float* v   = (const float*)d_in[1];
  const int* aidx  = (const int*)d_in[2];
  const int* iidx  = (const int*)d_in[3];
  // d_in[4] = labels (unused by the loss)

  char* ws = (char*)d_ws;
  const size_t MB = 1024 * 1024;
  __hip_bfloat16* Xv = (__hip_bfloat16*)(ws + 0 * MB);
  __hip_bfloat16* Ya = (__hip_bfloat16*)(ws + 1 * MB);
  __hip_bfloat16* Xa = (__hip_bfloat16*)(ws + 2 * MB);
  __hip_bfloat16* Yv = (__hip_bfloat16*)(ws + 3 * MB);
  float* diag   = (float*)(ws + 4 * MB);             // [2][8192]
  float* rowsum = (float*)(ws + 4 * MB + 64 * 1024); // [2][8192]

  gather_k<<<BN / 4, 256, 0, stream>>>(a, v, aidx, iidx, Xv, Ya, Xa, Yv,
                                       diag, rowsum, (float*)d_out);
  lse_main<<<dim3(BN / 128, 8, 2), 256, 0, stream>>>(
      (const unsigned short*)Xv, (const unsigned short*)Ya,
      (const unsigned short*)Xa, (const unsigned short*)Yv, rowsum);
  finalize_k<<<64, 256, 0, stream>>>(rowsum, diag, (float*)d_out);
}

// Round 4
// 93.319 us; speedup vs baseline: 1.0044x; 1.0044x over previous
//
#include <hip/hip_runtime.h>
#include <hip/hip_bf16.h>

typedef __attribute__((ext_vector_type(8))) short bf16x8;    // 8 bf16 = 4 VGPRs
typedef __attribute__((ext_vector_type(4))) float f32x4;
typedef __attribute__((ext_vector_type(16))) float f32x16;

#define BN 8192          // batch
#define DF 128           // feature dim
#define DG 64            // gathered dim
static constexpr float L2E = 1.44269504088896340736f;  // log2(e)
static constexpr float LN2 = 0.69314718055994530942f;

// Fragment-linear layout for 32x32x16 MFMA tiles (R10, kept).
// Per 32-row tile (2048 shorts = 4KB): element (row, k) lives at
//   tile*2048 + (k>>4)*512 + ((((k>>3)&1)*32 + (row&31))*8) + (k&7)
// i.e. lane = (k_hi8)*32 + m, elem c = k&7 -- canonical A/B layout for
// v_mfma_f32_32x32x16_bf16; a wave's fragment load for K-step kk is
// base + kk*512 shorts + lane*16B -> contiguous 1KB.
__device__ __forceinline__ size_t frag_off32(int row, int d) {
  int tile = row >> 5;
  int kk = d >> 4, khi = (d >> 3) & 1, c = d & 7;
  return (size_t)tile * 2048 + (size_t)kk * 512 +
         (size_t)(khi * 32 + (row & 31)) * 8 + c;
}

// ---------------------------------------------------------------------------
// Kernel 1: gather columns, convert to bf16 (X-side pre-scaled by log2 e),
// write 32-row fragment-linear layout, exact fp32 diagonals, zero rowsum/out.
// One wave per row; coalesced float2 row loads + in-register __shfl gather.
// ---------------------------------------------------------------------------
__global__ __launch_bounds__(256) void gather_k(
    const float* __restrict__ a, const float* __restrict__ v,
    const int* __restrict__ aidx, const int* __restrict__ iidx,
    __hip_bfloat16* __restrict__ Xv, __hip_bfloat16* __restrict__ Ya,
    __hip_bfloat16* __restrict__ Xa, __hip_bfloat16* __restrict__ Yv,
    float* __restrict__ diag, float* __restrict__ rowsum,
    float* __restrict__ out) {
  int tid = threadIdx.x;
  int gid = blockIdx.x * 256 + tid;
  if (gid < 2 * BN) rowsum[gid] = 0.f;    // zero accumulators (ws is poisoned)
  if (gid == 0) out[0] = 0.f;             // d_out is poisoned too

  int lane = tid & 63;
  int row  = blockIdx.x * 4 + (tid >> 6); // 2048 blocks x 4 waves = 8192 rows
  int ka = aidx[lane];
  int ki = iidx[lane];

  // coalesced: lane l holds elements (2l, 2l+1) of this row of a and v
  float2 a2 = ((const float2*)(a + (size_t)row * DF))[lane];
  float2 v2 = ((const float2*)(v + (size_t)row * DF))[lane];

  // in-register gather: element k lives in lane k>>1, component k&1
  float axa = __shfl(a2.x, ka >> 1), aya = __shfl(a2.y, ka >> 1);
  float vxa = __shfl(v2.x, ka >> 1), vya = __shfl(v2.y, ka >> 1);
  float axi = __shfl(a2.x, ki >> 1), ayi = __shfl(a2.y, ki >> 1);
  float vxi = __shfl(v2.x, ki >> 1), vyi = __shfl(v2.y, ki >> 1);
  float aa = (ka & 1) ? aya : axa;   // audio_only        (S_v cols)
  float va = (ka & 1) ? vya : vxa;   // image_audio_only  (S_v rows)
  float ai = (ki & 1) ? ayi : axi;   // audio_image_only  (S_a rows)
  float vi = (ki & 1) ? vyi : vxi;   // image_only        (S_a cols)

  size_t fo = frag_off32(row, lane);
  Xv[fo] = __float2bfloat16(va * L2E);
  Ya[fo] = __float2bfloat16(aa);
  Xa[fo] = __float2bfloat16(ai * L2E);
  Yv[fo] = __float2bfloat16(vi);

  // exact fp32 diagonals: diag_v[i] = dot(v_gath_a[i], a_gath_a[i]), etc.
  float dv = va * aa;
  float da = ai * vi;
#pragma unroll
  for (int off = 32; off >= 1; off >>= 1) {
    dv += __shfl_xor(dv, off);
    da += __shfl_xor(da, off);
  }
  if (lane == 0) {
    diag[row]      = dv;
    diag[BN + row] = da;
  }
}

// ---------------------------------------------------------------------------
// Kernel 2: partial sum_j 2^(S_ij) via mfma_f32_32x32x16_bf16.
// R11: break the pipe convoy. R7-R10 all land at the SERIAL SUM of
// trans(32.8k) + mfma + valu cycles per SIMD: identical waves stay
// phase-converged, so during the collective 16-exp2 cluster the matrix pipe
// idles and vice versa. Fix: fuse tile t's 4-deep MFMA chain with tile
// t-1's 16 exp2 at instruction granularity (4 exp2 before each mfma — the
// exp2s also cover the dependent-chain latency), and pin the emitted order
// with sched_group_barrier: per tile {TRANS 4, MFMA 1}x4 + {VMEM_READ 4}.
// setprio removed (null in R9; can't reduce the trans total).
// C layout (verified m74/m101): col=lane&31, row=(reg&3)+8*(reg>>2)+4*(lane>>5).
// ---------------------------------------------------------------------------
__global__ __launch_bounds__(256, 4) void lse_main(
    const unsigned short* __restrict__ Xv, const unsigned short* __restrict__ Ya,
    const unsigned short* __restrict__ Xa, const unsigned short* __restrict__ Yv,
    float* __restrict__ rowsum) {
  const unsigned short* X;
  const unsigned short* Y;
  float* rs;
  if (blockIdx.z == 0) { X = Xv; Y = Ya; rs = rowsum; }
  else                 { X = Xa; Y = Yv; rs = rowsum + BN; }

  int tid  = threadIdx.x;
  int lane = tid & 63;
  int row0 = blockIdx.x * 128 + (tid >> 6) * 32;   // one 32-row tile per wave

  // A fragments: 4 K-steps of 16, 1KB contiguous per step
  const unsigned short* ap =
      X + (size_t)(row0 >> 5) * 2048 + (size_t)lane * 8;
  bf16x8 a[4];
#pragma unroll
  for (int kk = 0; kk < 4; ++kk) a[kk] = *(const bf16x8*)(ap + kk * 512);

  // B base: this block sweeps 32 j-tiles of 32 cols (1024 cols)
  const unsigned short* bbase =
      Y + (size_t)(blockIdx.y * 32) * 2048 + (size_t)lane * 8;

  const f32x16 zero16 = {};
  f32x16 part = {};
  bf16x8 b[4];

#define LOADB(T)                                                              \
  {                                                                           \
    const unsigned short* p = bbase + (size_t)(T) * 2048;                     \
    b[0] = *(const bf16x8*)p;                                                 \
    b[1] = *(const bf16x8*)(p + 512);                                         \
    b[2] = *(const bf16x8*)(p + 1024);                                        \
    b[3] = *(const bf16x8*)(p + 1536);                                        \
  }
#define E4(CP, R0)                                                            \
  part[R0]     += __builtin_amdgcn_exp2f(CP[R0]);                             \
  part[R0 + 1] += __builtin_amdgcn_exp2f(CP[R0 + 1]);                         \
  part[R0 + 2] += __builtin_amdgcn_exp2f(CP[R0 + 2]);                         \
  part[R0 + 3] += __builtin_amdgcn_exp2f(CP[R0 + 3]);
// mfma tile -> DST while exp-accumulating previous tile CP, interleaved
#define CHAINEXP(DST, CP)                                                     \
  {                                                                           \
    E4(CP, 0)                                                                 \
    DST = __builtin_amdgcn_mfma_f32_32x32x16_bf16(a[0], b[0], zero16, 0, 0, 0); \
    E4(CP, 4)                                                                 \
    DST = __builtin_amdgcn_mfma_f32_32x32x16_bf16(a[1], b[1], DST, 0, 0, 0);  \
    E4(CP, 8)                                                                 \
    DST = __builtin_amdgcn_mfma_f32_32x32x16_bf16(a[2], b[2], DST, 0, 0, 0);  \
    E4(CP, 12)                                                                \
    DST = __builtin_amdgcn_mfma_f32_32x32x16_bf16(a[3], b[3], DST, 0, 0, 0);  \
  }
#define CHAIN(DST)                                                            \
  {                                                                           \
    DST = __builtin_amdgcn_mfma_f32_32x32x16_bf16(a[0], b[0], zero16, 0, 0, 0); \
    DST = __builtin_amdgcn_mfma_f32_32x32x16_bf16(a[1], b[1], DST, 0, 0, 0);  \
    DST = __builtin_amdgcn_mfma_f32_32x32x16_bf16(a[2], b[2], DST, 0, 0, 0);  \
    DST = __builtin_amdgcn_mfma_f32_32x32x16_bf16(a[3], b[3], DST, 0, 0, 0);  \
  }
#define EXPACC(C)                                                             \
  {                                                                           \
    _Pragma("unroll") for (int r = 0; r < 16; ++r)                            \
        part[r] += __builtin_amdgcn_exp2f(C[r]);                              \
  }
// sched_group_barrier masks: VALU=0x2, MFMA=0x8, VMEM_READ=0x20, TRANS=0x400
#define SGB(m, n) __builtin_amdgcn_sched_group_barrier(m, n, 0)
#define PIN_TILE                                                              \
  SGB(0x400, 4); SGB(0x8, 1);                                                 \
  SGB(0x400, 4); SGB(0x8, 1);                                                 \
  SGB(0x400, 4); SGB(0x8, 1);                                                 \
  SGB(0x400, 4); SGB(0x8, 1);                                                 \
  SGB(0x20, 4);

  f32x16 c0, c1;
  // prologue: tile 0 -> c0, prefetch tile 1
  LOADB(0)
  CHAIN(c0)
  LOADB(1)
  // steady state: 15 iterations x 2 tiles; loads stay exactly 1 tile ahead
  for (int i = 0; i < 15; ++i) {
    int t = 2 * i + 1;
    CHAINEXP(c1, c0)     // mfma tile t      || exp tile t-1
    LOADB(t + 1)
    PIN_TILE
    CHAINEXP(c0, c1)     // mfma tile t+1    || exp tile t
    LOADB(t + 2)         // max t=29 -> loads tile 31; no overrun
    PIN_TILE
  }
  // epilogue: tile 31 in b
  CHAINEXP(c1, c0)       // mfma tile 31 || exp tile 30
  EXPACC(c1)             // exp tile 31
#undef LOADB
#undef E4
#undef CHAINEXP
#undef CHAIN
#undef EXPACC
#undef SGB
#undef PIN_TILE

  // row sums: reduce part[r] across the 32 lanes of each half (cols)
#pragma unroll
  for (int off = 1; off < 32; off <<= 1) {
#pragma unroll
    for (int r = 0; r < 16; ++r)
      part[r] += __shfl_xor(part[r], off);
  }
  if ((lane & 31) == 0) {
    int hi = lane >> 5;
#pragma unroll
    for (int r = 0; r < 16; ++r) {
      int row = (r & 3) + 8 * (r >> 2) + 4 * hi;
      atomicAdd(&rs[row0 + row], part[r]);
    }
  }
}

// ---------------------------------------------------------------------------
// Kernel 3: 64-block finalize: out += sum(ln2*log2(rowsum) - diag) / BN
// (d_out zeroed by gather_k). __builtin_amdgcn_logf IS v_log_f32 = log2.
// ---------------------------------------------------------------------------
__global__ __launch_bounds__(256) void finalize_k(
    const float* __restrict__ rowsum, const float* __restrict__ diag,
    float* __restrict__ out) {
  int i = blockIdx.x * 256 + threadIdx.x;          // 64*256 = 16384 = 2*BN
  float local = LN2 * __builtin_amdgcn_logf(rowsum[i]) - diag[i];
#pragma unroll
  for (int off = 32; off >= 1; off >>= 1) local += __shfl_xor(local, off);
  __shared__ float red[4];
  int wave = threadIdx.x >> 6;
  if ((threadIdx.x & 63) == 0) red[wave] = local;
  __syncthreads();
  if (threadIdx.x == 0) {
    float bs = red[0] + red[1] + red[2] + red[3];
    atomicAdd(out, bs * (1.f / (float)BN));
  }
}

// ---------------------------------------------------------------------------
extern "C" void kernel_launch(void* const* d_in, const int* in_sizes, int n_in,
                              void* d_out, int out_size, void* d_ws, size_t ws_size,
                              hipStream_t stream) {
  const float* a   = (const float*)d_in[0];
  const float* v   = (const float*)d_in[1];
  const int* aidx  = (const int*)d_in[2];
  const int* iidx  = (const int*)d_in[3];
  // d_in[4] = labels (unused by the loss)

  char* ws = (char*)d_ws;
  const size_t MB = 1024 * 1024;
  __hip_bfloat16* Xv = (__hip_bfloat16*)(ws + 0 * MB);
  __hip_bfloat16* Ya = (__hip_bfloat16*)(ws + 1 * MB);
  __hip_bfloat16* Xa = (__hip_bfloat16*)(ws + 2 * MB);
  __hip_bfloat16* Yv = (__hip_bfloat16*)(ws + 3 * MB);
  float* diag   = (float*)(ws + 4 * MB);             // [2][8192]
  float* rowsum = (float*)(ws + 4 * MB + 64 * 1024); // [2][8192]

  gather_k<<<BN / 4, 256, 0, stream>>>(a, v, aidx, iidx, Xv, Ya, Xa, Yv,
                                       diag, rowsum, (float*)d_out);
  lse_main<<<dim3(BN / 128, 8, 2), 256, 0, stream>>>(
      (const unsigned short*)Xv, (const unsigned short*)Ya,
      (const unsigned short*)Xa, (const unsigned short*)Yv, rowsum);
  finalize_k<<<64, 256, 0, stream>>>(rowsum, diag, (float*)d_out);
}